// Round 9
// baseline (1246.018 us; speedup 1.0000x reference)
//
#include <hip/hip_runtime.h>
#include <cstdint>
#include <cstddef>

// -------- GCN 2-layer: out = A_norm @ prelu(A_norm @ (x W1) + b1) @ W2 + b2 --------
// A_norm = D^-1/2 (A + I) D^-1/2, deg = in-degree + 1 (PyG GCNConv default).
// edge_index arrives int32 [2][E]: src = ei[e], dst = ei[E + e].
//
// Round 9 = round 8 + tail-shfl fix: __shfl must execute with an ACTIVE source
// lane; previously it sat inside a divergent branch whose predicate differs per
// eslot group -> undefined reads for most nodes (absmax 8.3e-2). Now the shfl is
// unconditional with a clamped source (< m, all lanes active); only the
// gather+accumulate is predicated.
//
// Column-group-partitioned aggregate: a 64B cache line == one 32-col bf16 slice;
// block cg=blockIdx&7 (round-robin -> XCD cg) gathers only slice cg of every row
// -> per-XCD gather working set 51.2 MB -> 6.4 MB (vs 4 MB L2). Wave = 1 node;
// four 16-lane groups process 4 edges in parallel (ushort2/lane), shfl-broadcast
// indices, x2 unroll, shfl_xor butterfly reduce. Final output uses non-temporal
// stores so the 100 MB stream doesn't evict Tp during aggregation.
// CSR: two-level bucketed build (passA/passB). GEMM: no-LDS MFMA hi/lo bf16 split.

#define IN_C 256
#define BSHIFT 9
#define BCAP 24576   // bucket capacity (avg ~16.3K edges/bucket; huge margin)

typedef __attribute__((ext_vector_type(8))) short bf16x8;
typedef __attribute__((ext_vector_type(4))) float f32x4;
typedef __attribute__((ext_vector_type(2))) float f32x2;

__device__ __forceinline__ ushort f2bf(float x) {
    union { float f; uint32_t u; } v; v.f = x;
    uint32_t r = v.u + 0x7FFF + ((v.u >> 16) & 1);   // round-to-nearest-even
    return (ushort)(r >> 16);
}
__device__ __forceinline__ float bf2f(ushort b) {
    union { uint32_t u; float f; } v; v.u = ((uint32_t)b) << 16;
    return v.f;
}

// ---------------- CSR build: passA (bucket scatter, 4096 edges/block) ----------------
__global__ __launch_bounds__(256) void passA(const int* __restrict__ ei,
                                             int* __restrict__ bucketCnt,
                                             int2* __restrict__ bucketBuf, int E, int NB) {
    __shared__ int hist[256];
    __shared__ int gbase[256];
    __shared__ int cur[256];
    int tid = threadIdx.x;
    hist[tid] = 0; cur[tid] = 0;
    __syncthreads();
    int e0 = blockIdx.x * 4096;
    int src_r[16], dst_r[16];
#pragma unroll
    for (int i = 0; i < 16; ++i) {
        int e = e0 + i * 256 + tid;
        if (e < E) {
            src_r[i] = ei[e];
            dst_r[i] = ei[(size_t)E + e];
            atomicAdd(&hist[dst_r[i] >> BSHIFT], 1);
        } else dst_r[i] = -1;
    }
    __syncthreads();
    if (tid < NB && hist[tid] > 0) gbase[tid] = atomicAdd(&bucketCnt[tid], hist[tid]);
    __syncthreads();
#pragma unroll
    for (int i = 0; i < 16; ++i) {
        if (dst_r[i] >= 0) {
            int b = dst_r[i] >> BSHIFT;
            int p = atomicAdd(&cur[b], 1);
            int pos = gbase[b] + p;
            if (pos < BCAP) bucketBuf[(size_t)b * BCAP + pos] = make_int2(src_r[i], dst_r[i]);
        }
    }
}

// ---------------- CSR build: bucket base scan (tiny) ----------------
__global__ void bucket_scan(const int* __restrict__ bucketCnt, int* __restrict__ bucket_base,
                            int* __restrict__ row_ptr, int NB, int N) {
    if (threadIdx.x == 0 && blockIdx.x == 0) {
        int run = 0;
        for (int b = 0; b < NB; ++b) {
            int c = bucketCnt[b]; if (c > BCAP) c = BCAP;
            bucket_base[b] = run; run += c;
        }
        row_ptr[N] = run;   // == E
    }
}

// ---------------- CSR build: passB (one block per bucket; local CSR in LDS) ----------------
__global__ __launch_bounds__(256) void passB(const int2* __restrict__ bucketBuf,
                                             const int* __restrict__ bucketCnt,
                                             const int* __restrict__ bucket_base,
                                             int* __restrict__ row_ptr,
                                             int* __restrict__ csr_src, int N) {
    __shared__ int cnt[512];
    __shared__ int ofs[512];
    __shared__ int ssum[256];
    int b = blockIdx.x, tid = threadIdx.x;
    int base_node = b << BSHIFT;
    int nnodes = N - base_node; if (nnodes > 512) nnodes = 512;
    int nE = bucketCnt[b]; if (nE > BCAP) nE = BCAP;
    const int2* buf = bucketBuf + (size_t)b * BCAP;
    cnt[tid] = 0; cnt[tid + 256] = 0;
    __syncthreads();
    for (int i = tid; i < nE; i += 256) {
        int2 p = buf[i];
        atomicAdd(&cnt[p.y - base_node], 1);
    }
    __syncthreads();
    int c0 = cnt[2 * tid], c1 = cnt[2 * tid + 1];
    int s = c0 + c1;
    ssum[tid] = s;
    __syncthreads();
    for (int o = 1; o < 256; o <<= 1) {
        int add = (tid >= o) ? ssum[tid - o] : 0;
        __syncthreads();
        ssum[tid] += add;
        __syncthreads();
    }
    int run = ssum[tid] - s;           // exclusive within bucket
    int gb = bucket_base[b];
    int o0 = gb + run, o1 = gb + run + c0;
    ofs[2 * tid] = o0; ofs[2 * tid + 1] = o1;
    if (2 * tid < nnodes)     row_ptr[base_node + 2 * tid]     = o0;
    if (2 * tid + 1 < nnodes) row_ptr[base_node + 2 * tid + 1] = o1;
    __syncthreads();
    for (int i = tid; i < nE; i += 256) {
        int2 p = buf[i];
        int pos = atomicAdd(&ofs[p.y - base_node], 1);
        csr_src[pos] = p.x;            // ~96KB window: L2-aggregated writeback
    }
}

// ---------------- dis from row_ptr diffs ----------------
__global__ __launch_bounds__(256) void dis2(const int* __restrict__ row_ptr,
                                            float* __restrict__ dis, int N) {
    int i = blockIdx.x * 256 + threadIdx.x;
    if (i < N) dis[i] = rsqrtf((float)(row_ptr[i + 1] - row_ptr[i] + 1));
}

// ---------------- split fp32 -> hi/lo bf16 planes ----------------
__global__ __launch_bounds__(256) void split_x(const float* __restrict__ x,
                                               ushort* __restrict__ Xh,
                                               ushort* __restrict__ Xl, int total4) {
    int id = blockIdx.x * 256 + threadIdx.x;   // unit = 4 floats
    if (id >= total4) return;
    float4 v = ((const float4*)x)[id];
    ushort hx = f2bf(v.x), hy = f2bf(v.y), hz = f2bf(v.z), hw = f2bf(v.w);
    ((ushort4*)Xh)[id] = make_ushort4(hx, hy, hz, hw);
    ((ushort4*)Xl)[id] = make_ushort4(f2bf(v.x - bf2f(hx)), f2bf(v.y - bf2f(hy)),
                                      f2bf(v.z - bf2f(hz)), f2bf(v.w - bf2f(hw)));
}

// ---------------- weight prep: W[k][n] f32 -> WT[n][k] hi/lo bf16 ----------------
__global__ __launch_bounds__(256) void prep_w(const float* __restrict__ W,
                                              ushort* __restrict__ WTh,
                                              ushort* __restrict__ WTl) {
    int id = blockIdx.x * 256 + threadIdx.x;   // 65536
    int n = id >> 8, k = id & 255;
    float w = W[k * 256 + n];
    ushort h = f2bf(w);
    WTh[id] = h;
    WTl[id] = f2bf(w - bf2f(h));
}

// ---------------- no-LDS MFMA GEMM: T'(bf16)[M][256] = dis[r] * (A @ W) ----------------
__global__ __launch_bounds__(256, 2) void gemm_split(const ushort* __restrict__ Ah,
                                                     const ushort* __restrict__ Al,
                                                     const ushort* __restrict__ Bh,
                                                     const ushort* __restrict__ Bl,
                                                     const float* __restrict__ dis,
                                                     ushort* __restrict__ C, int M) {
    int gw = blockIdx.x * 4 + (threadIdx.x >> 6);
    int lane = threadIdx.x & 63;
    int wr = gw >> 1, wc = gw & 1;
    int row0 = wr * 64, col0 = wc * 128;
    if (row0 >= M) return;
    int lrow = lane & 15, lk = (lane >> 4) * 8;

    f32x4 acc[4][8];
#pragma unroll
    for (int i = 0; i < 4; ++i)
#pragma unroll
        for (int j = 0; j < 8; ++j) acc[i][j] = (f32x4)0.f;

#pragma unroll
    for (int ks = 0; ks < 8; ++ks) {
        int kb = ks * 32 + lk;
        bf16x8 ah[4], al[4];
#pragma unroll
        for (int i = 0; i < 4; ++i) {
            int row = row0 + i * 16 + lrow;
            if (row < M) {
                ah[i] = *(const bf16x8*)&Ah[(size_t)row * 256 + kb];
                al[i] = *(const bf16x8*)&Al[(size_t)row * 256 + kb];
            } else {
                ah[i] = (bf16x8)(short)0;
                al[i] = (bf16x8)(short)0;
            }
        }
#pragma unroll
        for (int j = 0; j < 8; ++j) {
            bf16x8 bh = *(const bf16x8*)&Bh[(size_t)(col0 + j * 16 + lrow) * 256 + kb];
            bf16x8 bl = *(const bf16x8*)&Bl[(size_t)(col0 + j * 16 + lrow) * 256 + kb];
#pragma unroll
            for (int i = 0; i < 4; ++i) {
                acc[i][j] = __builtin_amdgcn_mfma_f32_16x16x32_bf16(ah[i], bh, acc[i][j], 0, 0, 0);
                acc[i][j] = __builtin_amdgcn_mfma_f32_16x16x32_bf16(ah[i], bl, acc[i][j], 0, 0, 0);
                acc[i][j] = __builtin_amdgcn_mfma_f32_16x16x32_bf16(al[i], bh, acc[i][j], 0, 0, 0);
            }
        }
    }
    // C/D layout (m89): col = lane&15, row = (lane>>4)*4 + reg
    int rb = (lane >> 4) * 4;
#pragma unroll
    for (int i = 0; i < 4; ++i) {
#pragma unroll
        for (int r = 0; r < 4; ++r) {
            int row = row0 + i * 16 + rb + r;
            if (row >= M) continue;
            float dr = dis[row];
#pragma unroll
            for (int j = 0; j < 8; ++j) {
                int col = col0 + j * 16 + lrow;
                C[(size_t)row * 256 + col] = f2bf(dr * acc[i][j][r]);
            }
        }
    }
}

// ------- column-group aggregate: out[n] = dis[n]*(T'[n] + sum_e T'[src_e]) + b -------
// block cg = blockIdx&7 handles 64B slice [cg*64, cg*64+64) of every row (one cache
// line) -> per-XCD gather working set 6.4 MB. Wave = 1 node; 16-lane groups (eslot)
// process 4 edges concurrently, 2 ushorts/lane; shfl-broadcast indices; x2 unroll;
// shfl_xor butterfly reduces the 4 edge-slots. eslot0 lanes write.
__global__ __launch_bounds__(1024) void aggregate_cg(const ushort* __restrict__ Tp,
                                                     const int* __restrict__ row_ptr,
                                                     const int* __restrict__ csr_src,
                                                     const float* __restrict__ dis,
                                                     const float* __restrict__ bias,
                                                     const float* __restrict__ alpha_p,
                                                     float* __restrict__ outf,
                                                     ushort* __restrict__ outh,
                                                     ushort* __restrict__ outl,
                                                     int N, int mode) {
    int cg = blockIdx.x & 7;
    int wave = threadIdx.x >> 6;
    int lane = threadIdx.x & 63;
    int n = (blockIdx.x >> 3) * 16 + wave;
    if (n >= N) return;
    int eslot = lane >> 4;
    int col = cg * 32 + (lane & 15) * 2;

    float accx = 0.f, accy = 0.f;
    if (eslot == 0) {
        ushort2 sv = *(const ushort2*)&Tp[(size_t)n * 256 + col];
        accx = bf2f(sv.x); accy = bf2f(sv.y);
    }
    int e0 = row_ptr[n], e1 = row_ptr[n + 1];
    for (int base = e0; base < e1; base += 64) {
        int m = e1 - base; if (m > 64) m = 64;
        int idx = csr_src[base + (lane < m ? lane : 0)];
        int j = 0;
        for (; j + 8 <= m; j += 8) {
            int sA = __shfl(idx, j + eslot);
            int sB = __shfl(idx, j + 4 + eslot);
            ushort2 vA = *(const ushort2*)&Tp[(size_t)sA * 256 + col];
            ushort2 vB = *(const ushort2*)&Tp[(size_t)sB * 256 + col];
            accx += bf2f(vA.x); accy += bf2f(vA.y);
            accx += bf2f(vB.x); accy += bf2f(vB.y);
        }
        // tail: shfl OUTSIDE the divergent branch, source lane clamped to < m so
        // it is always an active lane (inactive-source shfl is undefined on CDNA).
        for (; j < m; j += 4) {
            int jj = j + eslot;
            int s = __shfl(idx, jj < m ? jj : (m - 1));
            if (jj < m) {
                ushort2 v = *(const ushort2*)&Tp[(size_t)s * 256 + col];
                accx += bf2f(v.x); accy += bf2f(v.y);
            }
        }
    }
    // butterfly reduce over the 4 edge-slots (lane bits 4,5)
    accx += __shfl_xor(accx, 16); accy += __shfl_xor(accy, 16);
    accx += __shfl_xor(accx, 32); accy += __shfl_xor(accy, 32);

    if (eslot == 0) {
        float dn = dis[n];
        float2 bv = *(const float2*)&bias[col];
        float rx = dn * accx + bv.x;
        float ry = dn * accy + bv.y;
        if (mode) {
            float al = *alpha_p;
            rx = rx >= 0.f ? rx : al * rx;
            ry = ry >= 0.f ? ry : al * ry;
            ushort2 hi, lo;
            hi.x = f2bf(rx); hi.y = f2bf(ry);
            lo.x = f2bf(rx - bf2f(hi.x)); lo.y = f2bf(ry - bf2f(hi.y));
            *(ushort2*)&outh[(size_t)n * 256 + col] = hi;
            *(ushort2*)&outl[(size_t)n * 256 + col] = lo;
        } else {
            f32x2 r; r.x = rx; r.y = ry;
            __builtin_nontemporal_store(r, (f32x2*)&outf[(size_t)n * 256 + col]);
        }
    }
}

extern "C" void kernel_launch(void* const* d_in, const int* in_sizes, int n_in,
                              void* d_out, int out_size, void* d_ws, size_t ws_size,
                              hipStream_t stream) {
    const float* x = (const float*)d_in[0];
    const int* ei = (const int*)d_in[1];          // int32 (harness converts int64 -> int32)
    const float* W1 = (const float*)d_in[2];
    const float* b1 = (const float*)d_in[3];
    const float* W2 = (const float*)d_in[4];
    const float* b2 = (const float*)d_in[5];
    const float* alpha = (const float*)d_in[6];
    int N = in_sizes[0] / IN_C;
    int E = in_sizes[1] / 2;
    int NB = (N + 511) >> BSHIFT;
    if (NB > 256) return;                          // clean fail on unexpected N

    // ---- workspace layout (~116 MB, within proven footprint) ----
    char* ws = (char*)d_ws;
    size_t off = 0;
    auto alloc = [&](size_t bytes) {
        void* p = ws + off;
        off = (off + bytes + 255) & ~(size_t)255;
        return p;
    };
    int* row_ptr     = (int*)alloc(((size_t)N + 1) * 4);
    float* dis       = (float*)alloc((size_t)N * 4);
    int* csr_src     = (int*)alloc((size_t)E * 4);
    int* bucketCnt   = (int*)alloc(256 * 4);
    int* bucket_base = (int*)alloc(256 * 4);
    ushort* Tp       = (ushort*)alloc((size_t)N * IN_C * 2);   // 51.2 MB (bucketBuf alias)
    ushort* Xl       = (ushort*)alloc((size_t)N * IN_C * 2);   // 51.2 MB (also Hl)
    if (off > ws_size) return;                     // clean fail if ws too small
    int2* bucketBuf = (int2*)Tp;                   // dead before gemm1 writes Tp
    if ((size_t)NB * BCAP * 8 > (size_t)N * IN_C * 2) return;  // alias capacity guard

    // ---- d_out doubles as scratch (dead before final write) ----
    char* dob = (char*)d_out;
    ushort* Xh  = (ushort*)dob;                                   // also Hh
    ushort* W1h = (ushort*)(dob + (size_t)N * IN_C * 2);
    ushort* W1l = W1h + 65536;
    ushort* W2h = W1h + 131072;
    ushort* W2l = W1h + 196608;
    float* outf = (float*)d_out;

    hipMemsetAsync(bucketCnt, 0, 256 * 4, stream);

    // ---- CSR build (bucketed) ----
    passA<<<(E + 4095) / 4096, 256, 0, stream>>>(ei, bucketCnt, bucketBuf, E, NB);
    bucket_scan<<<1, 64, 0, stream>>>(bucketCnt, bucket_base, row_ptr, NB, N);
    passB<<<NB, 256, 0, stream>>>(bucketBuf, bucketCnt, bucket_base, row_ptr, csr_src, N);
    int nb256 = (N + 255) / 256;
    dis2<<<nb256, 256, 0, stream>>>(row_ptr, dis, N);

    // ---- precision prep ----
    int total4 = N * (IN_C / 4);
    split_x<<<(total4 + 255) / 256, 256, 0, stream>>>(x, Xh, Xl, total4);
    prep_w<<<256, 256, 0, stream>>>(W1, W1h, W1l);
    prep_w<<<256, 256, 0, stream>>>(W2, W2h, W2l);

    int nrow_t = (N + 63) / 64;
    int gblocks = (nrow_t * 2 + 3) / 4;
    int agg_blocks = 8 * ((N + 15) / 16);

    // layer 1: T' = dis * (x@W1);  H(hi/lo) = prelu(dn*(T'n + sum T's) + b1)
    gemm_split<<<gblocks, 256, 0, stream>>>(Xh, Xl, W1h, W1l, dis, Tp, N);
    aggregate_cg<<<agg_blocks, 1024, 0, stream>>>(Tp, row_ptr, csr_src, dis, b1, alpha,
                                                  nullptr, Xh /*Hh*/, Xl /*Hl*/, N, 1);
    // layer 2: T' = dis * (H@W2);  out = dn*(T'n + sum T's) + b2
    gemm_split<<<gblocks, 256, 0, stream>>>(Xh /*Hh*/, Xl /*Hl*/, W2h, W2l, dis, Tp, N);
    aggregate_cg<<<agg_blocks, 1024, 0, stream>>>(Tp, row_ptr, csr_src, dis, b2, alpha,
                                                  outf, nullptr, nullptr, N, 0);
}

// Round 10
// 723.431 us; speedup vs baseline: 1.7224x; 1.7224x over previous
//
#include <hip/hip_runtime.h>
#include <cstdint>
#include <cstddef>

// -------- GCN 2-layer: out = A_norm @ prelu(A_norm @ (x W1) + b1) @ W2 + b2 --------
// A_norm = D^-1/2 (A + I) D^-1/2, deg = in-degree + 1 (PyG GCNConv default).
// edge_index arrives int32 [2][E]: src = ei[e], dst = ei[E + e].
//
// Round 10: (a) REVERT aggregate to the round-6 full-row structure (column-group
// split regressed: 8x index re-reads + lost intra-row line reuse), deepen ILP to
// 8 independent gather accumulators (round 6 was concurrency-limited: 3.9/6.3 TB/s,
// VALU 25%). (b) GEMM: stage B hi/lo in LDS (132 KB, +8 pad -> <=2-way conflicts);
// the no-LDS version was L2-BW-bound on B-fragment re-reads. 512-thr blocks
// (8 waves, 2/SIMD), per-wave 64x128 tile, A from global, 3-term hi/lo bf16 split.
// CSR: two-level bucketed build. dis folded into GEMM epilogue.

#define IN_C 256
#define BSHIFT 9
#define BCAP 24576   // bucket capacity (avg ~16.3K edges/bucket; huge margin)

typedef __attribute__((ext_vector_type(8))) short bf16x8;
typedef __attribute__((ext_vector_type(4))) float f32x4;

__device__ __forceinline__ ushort f2bf(float x) {
    union { float f; uint32_t u; } v; v.f = x;
    uint32_t r = v.u + 0x7FFF + ((v.u >> 16) & 1);   // round-to-nearest-even
    return (ushort)(r >> 16);
}
__device__ __forceinline__ float bf2f(ushort b) {
    union { uint32_t u; float f; } v; v.u = ((uint32_t)b) << 16;
    return v.f;
}

// ---------------- CSR build: passA (bucket scatter, 4096 edges/block) ----------------
__global__ __launch_bounds__(256) void passA(const int* __restrict__ ei,
                                             int* __restrict__ bucketCnt,
                                             int2* __restrict__ bucketBuf, int E, int NB) {
    __shared__ int hist[256];
    __shared__ int gbase[256];
    __shared__ int cur[256];
    int tid = threadIdx.x;
    hist[tid] = 0; cur[tid] = 0;
    __syncthreads();
    int e0 = blockIdx.x * 4096;
    int src_r[16], dst_r[16];
#pragma unroll
    for (int i = 0; i < 16; ++i) {
        int e = e0 + i * 256 + tid;
        if (e < E) {
            src_r[i] = ei[e];
            dst_r[i] = ei[(size_t)E + e];
            atomicAdd(&hist[dst_r[i] >> BSHIFT], 1);
        } else dst_r[i] = -1;
    }
    __syncthreads();
    if (tid < NB && hist[tid] > 0) gbase[tid] = atomicAdd(&bucketCnt[tid], hist[tid]);
    __syncthreads();
#pragma unroll
    for (int i = 0; i < 16; ++i) {
        if (dst_r[i] >= 0) {
            int b = dst_r[i] >> BSHIFT;
            int p = atomicAdd(&cur[b], 1);
            int pos = gbase[b] + p;
            if (pos < BCAP) bucketBuf[(size_t)b * BCAP + pos] = make_int2(src_r[i], dst_r[i]);
        }
    }
}

// ---------------- CSR build: bucket base scan (tiny) ----------------
__global__ void bucket_scan(const int* __restrict__ bucketCnt, int* __restrict__ bucket_base,
                            int* __restrict__ row_ptr, int NB, int N) {
    if (threadIdx.x == 0 && blockIdx.x == 0) {
        int run = 0;
        for (int b = 0; b < NB; ++b) {
            int c = bucketCnt[b]; if (c > BCAP) c = BCAP;
            bucket_base[b] = run; run += c;
        }
        row_ptr[N] = run;   // == E
    }
}

// ---------------- CSR build: passB (one block per bucket; local CSR in LDS) ----------------
__global__ __launch_bounds__(256) void passB(const int2* __restrict__ bucketBuf,
                                             const int* __restrict__ bucketCnt,
                                             const int* __restrict__ bucket_base,
                                             int* __restrict__ row_ptr,
                                             int* __restrict__ csr_src, int N) {
    __shared__ int cnt[512];
    __shared__ int ofs[512];
    __shared__ int ssum[256];
    int b = blockIdx.x, tid = threadIdx.x;
    int base_node = b << BSHIFT;
    int nnodes = N - base_node; if (nnodes > 512) nnodes = 512;
    int nE = bucketCnt[b]; if (nE > BCAP) nE = BCAP;
    const int2* buf = bucketBuf + (size_t)b * BCAP;
    cnt[tid] = 0; cnt[tid + 256] = 0;
    __syncthreads();
    for (int i = tid; i < nE; i += 256) {
        int2 p = buf[i];
        atomicAdd(&cnt[p.y - base_node], 1);
    }
    __syncthreads();
    int c0 = cnt[2 * tid], c1 = cnt[2 * tid + 1];
    int s = c0 + c1;
    ssum[tid] = s;
    __syncthreads();
    for (int o = 1; o < 256; o <<= 1) {
        int add = (tid >= o) ? ssum[tid - o] : 0;
        __syncthreads();
        ssum[tid] += add;
        __syncthreads();
    }
    int run = ssum[tid] - s;           // exclusive within bucket
    int gb = bucket_base[b];
    int o0 = gb + run, o1 = gb + run + c0;
    ofs[2 * tid] = o0; ofs[2 * tid + 1] = o1;
    if (2 * tid < nnodes)     row_ptr[base_node + 2 * tid]     = o0;
    if (2 * tid + 1 < nnodes) row_ptr[base_node + 2 * tid + 1] = o1;
    __syncthreads();
    for (int i = tid; i < nE; i += 256) {
        int2 p = buf[i];
        int pos = atomicAdd(&ofs[p.y - base_node], 1);
        csr_src[pos] = p.x;            // ~96KB window: L2-aggregated writeback
    }
}

// ---------------- dis from row_ptr diffs ----------------
__global__ __launch_bounds__(256) void dis2(const int* __restrict__ row_ptr,
                                            float* __restrict__ dis, int N) {
    int i = blockIdx.x * 256 + threadIdx.x;
    if (i < N) dis[i] = rsqrtf((float)(row_ptr[i + 1] - row_ptr[i] + 1));
}

// ---------------- split fp32 -> hi/lo bf16 planes ----------------
__global__ __launch_bounds__(256) void split_x(const float* __restrict__ x,
                                               ushort* __restrict__ Xh,
                                               ushort* __restrict__ Xl, int total4) {
    int id = blockIdx.x * 256 + threadIdx.x;   // unit = 4 floats
    if (id >= total4) return;
    float4 v = ((const float4*)x)[id];
    ushort hx = f2bf(v.x), hy = f2bf(v.y), hz = f2bf(v.z), hw = f2bf(v.w);
    ((ushort4*)Xh)[id] = make_ushort4(hx, hy, hz, hw);
    ((ushort4*)Xl)[id] = make_ushort4(f2bf(v.x - bf2f(hx)), f2bf(v.y - bf2f(hy)),
                                      f2bf(v.z - bf2f(hz)), f2bf(v.w - bf2f(hw)));
}

// ---------------- weight prep: W[k][n] f32 -> WT[n][k] hi/lo bf16 ----------------
__global__ __launch_bounds__(256) void prep_w(const float* __restrict__ W,
                                              ushort* __restrict__ WTh,
                                              ushort* __restrict__ WTl) {
    int id = blockIdx.x * 256 + threadIdx.x;   // 65536
    int n = id >> 8, k = id & 255;
    float w = W[k * 256 + n];
    ushort h = f2bf(w);
    WTh[id] = h;
    WTl[id] = f2bf(w - bf2f(h));
}

// ------- LDS-B MFMA GEMM: T'(bf16)[M][256] = dis[r] * (A @ W) -------
// Block: 512 thr (8 waves), 512 rows x 128 cols. B hi/lo staged in LDS (132 KB,
// +8 ushort pad -> <=2-way read conflicts). Per-wave 64x128, A frags from global.
__global__ __launch_bounds__(512, 2) void gemm_lds(const ushort* __restrict__ Ah,
                                                   const ushort* __restrict__ Al,
                                                   const ushort* __restrict__ Bh,
                                                   const ushort* __restrict__ Bl,
                                                   const float* __restrict__ dis,
                                                   ushort* __restrict__ C, int M) {
    __shared__ ushort Bsh[128][264];
    __shared__ ushort Bsl[128][264];
    int tid = threadIdx.x;
    int col0 = (blockIdx.x & 1) << 7;
    int brow = (blockIdx.x >> 1) << 9;
    // stage B: 128 cols x 256 k x 2 planes; unit = 8 ushorts (16B), coalesced
#pragma unroll
    for (int i = 0; i < 8; ++i) {
        int u = tid + i * 512;          // 4096 units per plane
        int cb = u >> 5, ko = (u & 31) * 8;
        *(bf16x8*)&Bsh[cb][ko] = *(const bf16x8*)&Bh[(size_t)(col0 + cb) * 256 + ko];
        *(bf16x8*)&Bsl[cb][ko] = *(const bf16x8*)&Bl[(size_t)(col0 + cb) * 256 + ko];
    }
    __syncthreads();

    int wave = tid >> 6, lane = tid & 63;
    int row0 = brow + wave * 64;
    if (row0 >= M) return;
    int lrow = lane & 15, lk = (lane >> 4) * 8;

    f32x4 acc[4][8];
#pragma unroll
    for (int i = 0; i < 4; ++i)
#pragma unroll
        for (int j = 0; j < 8; ++j) acc[i][j] = (f32x4)0.f;

#pragma unroll
    for (int ks = 0; ks < 8; ++ks) {
        int kb = ks * 32 + lk;
        bf16x8 ah[4], al[4];
#pragma unroll
        for (int i = 0; i < 4; ++i) {
            int row = row0 + i * 16 + lrow;
            if (row < M) {
                ah[i] = *(const bf16x8*)&Ah[(size_t)row * 256 + kb];
                al[i] = *(const bf16x8*)&Al[(size_t)row * 256 + kb];
            } else {
                ah[i] = (bf16x8)(short)0;
                al[i] = (bf16x8)(short)0;
            }
        }
#pragma unroll
        for (int j = 0; j < 8; ++j) {
            bf16x8 bh = *(bf16x8*)&Bsh[j * 16 + lrow][kb];
            bf16x8 bl = *(bf16x8*)&Bsl[j * 16 + lrow][kb];
#pragma unroll
            for (int i = 0; i < 4; ++i) {
                acc[i][j] = __builtin_amdgcn_mfma_f32_16x16x32_bf16(ah[i], bh, acc[i][j], 0, 0, 0);
                acc[i][j] = __builtin_amdgcn_mfma_f32_16x16x32_bf16(ah[i], bl, acc[i][j], 0, 0, 0);
                acc[i][j] = __builtin_amdgcn_mfma_f32_16x16x32_bf16(al[i], bh, acc[i][j], 0, 0, 0);
            }
        }
    }
    // C/D layout (m89): col = lane&15, row = (lane>>4)*4 + reg
    int rb = (lane >> 4) * 4;
#pragma unroll
    for (int i = 0; i < 4; ++i) {
#pragma unroll
        for (int r = 0; r < 4; ++r) {
            int row = row0 + i * 16 + rb + r;
            if (row >= M) continue;
            float dr = dis[row];
#pragma unroll
            for (int j = 0; j < 8; ++j) {
                int col = col0 + j * 16 + lrow;
                C[(size_t)row * 256 + col] = f2bf(dr * acc[i][j][r]);
            }
        }
    }
}

// ---------------- aggregate: out[n] = dis[n]*(T'[n] + sum_e T'[src_e]) + b ----------------
// one wave per node; lane covers 4 cols (8 B). 64-edge batched coalesced index
// loads, readlane broadcast (uniform, EXEC-safe), x8 unroll with 8 independent
// accumulators -> 8 gathers of 512B in flight. mode 1: PReLU + hi/lo planes.
__global__ __launch_bounds__(256) void aggregate8(const ushort* __restrict__ Tp,
                                                  const int* __restrict__ row_ptr,
                                                  const int* __restrict__ csr_src,
                                                  const float* __restrict__ dis,
                                                  const float* __restrict__ bias,
                                                  const float* __restrict__ alpha_p,
                                                  float* __restrict__ outf,
                                                  ushort* __restrict__ outh,
                                                  ushort* __restrict__ outl,
                                                  int N, int mode) {
    int wave = threadIdx.x >> 6;
    int lane = threadIdx.x & 63;
    int n = blockIdx.x * 4 + wave;
    if (n >= N) return;
    int c = lane * 4;

    float ax[8], ay[8], az[8], aw[8];
#pragma unroll
    for (int t = 0; t < 8; ++t) { ax[t] = 0.f; ay[t] = 0.f; az[t] = 0.f; aw[t] = 0.f; }
    {
        ushort4 sv = *(const ushort4*)&Tp[(size_t)n * 256 + c];
        ax[0] = bf2f(sv.x); ay[0] = bf2f(sv.y); az[0] = bf2f(sv.z); aw[0] = bf2f(sv.w);
    }

    int e0 = row_ptr[n], e1 = row_ptr[n + 1];
    for (int base = e0; base < e1; base += 64) {
        int rem = e1 - base;
        int m = rem < 64 ? rem : 64;
        int idx = csr_src[base + (lane < m ? lane : 0)];
        int j = 0;
        for (; j + 8 <= m; j += 8) {
            int s[8];
            ushort4 v[8];
#pragma unroll
            for (int t = 0; t < 8; ++t) s[t] = __builtin_amdgcn_readlane(idx, j + t);
#pragma unroll
            for (int t = 0; t < 8; ++t) v[t] = *(const ushort4*)&Tp[(size_t)s[t] * 256 + c];
#pragma unroll
            for (int t = 0; t < 8; ++t) {
                ax[t] += bf2f(v[t].x); ay[t] += bf2f(v[t].y);
                az[t] += bf2f(v[t].z); aw[t] += bf2f(v[t].w);
            }
        }
        for (; j < m; ++j) {
            int s = __builtin_amdgcn_readlane(idx, j);
            ushort4 v = *(const ushort4*)&Tp[(size_t)s * 256 + c];
            ax[0] += bf2f(v.x); ay[0] += bf2f(v.y); az[0] += bf2f(v.z); aw[0] += bf2f(v.w);
        }
    }
#pragma unroll
    for (int t = 1; t < 8; ++t) { ax[0] += ax[t]; ay[0] += ay[t]; az[0] += az[t]; aw[0] += aw[t]; }

    float dn = dis[n];
    float4 bv = *(const float4*)&bias[c];
    float rx = dn * ax[0] + bv.x;
    float ry = dn * ay[0] + bv.y;
    float rz = dn * az[0] + bv.z;
    float rw = dn * aw[0] + bv.w;
    if (mode) {
        float al = *alpha_p;
        rx = rx >= 0.f ? rx : al * rx;
        ry = ry >= 0.f ? ry : al * ry;
        rz = rz >= 0.f ? rz : al * rz;
        rw = rw >= 0.f ? rw : al * rw;
        ushort hx = f2bf(rx), hy = f2bf(ry), hz = f2bf(rz), hw = f2bf(rw);
        *(ushort4*)&outh[(size_t)n * 256 + c] = make_ushort4(hx, hy, hz, hw);
        *(ushort4*)&outl[(size_t)n * 256 + c] = make_ushort4(f2bf(rx - bf2f(hx)), f2bf(ry - bf2f(hy)),
                                                             f2bf(rz - bf2f(hz)), f2bf(rw - bf2f(hw)));
    } else {
        f32x4 r; r.x = rx; r.y = ry; r.z = rz; r.w = rw;
        __builtin_nontemporal_store(r, (f32x4*)&outf[(size_t)n * 256 + c]);
    }
}

extern "C" void kernel_launch(void* const* d_in, const int* in_sizes, int n_in,
                              void* d_out, int out_size, void* d_ws, size_t ws_size,
                              hipStream_t stream) {
    const float* x = (const float*)d_in[0];
    const int* ei = (const int*)d_in[1];          // int32 (harness converts int64 -> int32)
    const float* W1 = (const float*)d_in[2];
    const float* b1 = (const float*)d_in[3];
    const float* W2 = (const float*)d_in[4];
    const float* b2 = (const float*)d_in[5];
    const float* alpha = (const float*)d_in[6];
    int N = in_sizes[0] / IN_C;
    int E = in_sizes[1] / 2;
    int NB = (N + 511) >> BSHIFT;
    if (NB > 256) return;                          // clean fail on unexpected N

    // ---- workspace layout (~116 MB, within proven footprint) ----
    char* ws = (char*)d_ws;
    size_t off = 0;
    auto alloc = [&](size_t bytes) {
        void* p = ws + off;
        off = (off + bytes + 255) & ~(size_t)255;
        return p;
    };
    int* row_ptr     = (int*)alloc(((size_t)N + 1) * 4);
    float* dis       = (float*)alloc((size_t)N * 4);
    int* csr_src     = (int*)alloc((size_t)E * 4);
    int* bucketCnt   = (int*)alloc(256 * 4);
    int* bucket_base = (int*)alloc(256 * 4);
    ushort* Tp       = (ushort*)alloc((size_t)N * IN_C * 2);   // 51.2 MB (bucketBuf alias)
    ushort* Xl       = (ushort*)alloc((size_t)N * IN_C * 2);   // 51.2 MB (also Hl)
    if (off > ws_size) return;                     // clean fail if ws too small
    int2* bucketBuf = (int2*)Tp;                   // dead before gemm1 writes Tp
    if ((size_t)NB * BCAP * 8 > (size_t)N * IN_C * 2) return;  // alias capacity guard

    // ---- d_out doubles as scratch (dead before final write) ----
    char* dob = (char*)d_out;
    ushort* Xh  = (ushort*)dob;                                   // also Hh
    ushort* W1h = (ushort*)(dob + (size_t)N * IN_C * 2);
    ushort* W1l = W1h + 65536;
    ushort* W2h = W1h + 131072;
    ushort* W2l = W1h + 196608;
    float* outf = (float*)d_out;

    hipMemsetAsync(bucketCnt, 0, 256 * 4, stream);

    // ---- CSR build (bucketed) ----
    passA<<<(E + 4095) / 4096, 256, 0, stream>>>(ei, bucketCnt, bucketBuf, E, NB);
    bucket_scan<<<1, 64, 0, stream>>>(bucketCnt, bucket_base, row_ptr, NB, N);
    passB<<<NB, 256, 0, stream>>>(bucketBuf, bucketCnt, bucket_base, row_ptr, csr_src, N);
    int nb256 = (N + 255) / 256;
    dis2<<<nb256, 256, 0, stream>>>(row_ptr, dis, N);

    // ---- precision prep ----
    int total4 = N * (IN_C / 4);
    split_x<<<(total4 + 255) / 256, 256, 0, stream>>>(x, Xh, Xl, total4);
    prep_w<<<256, 256, 0, stream>>>(W1, W1h, W1l);
    prep_w<<<256, 256, 0, stream>>>(W2, W2h, W2l);

    int gblocks = ((N + 511) / 512) * 2;
    int ablocks = (N + 3) / 4;

    // layer 1: T' = dis * (x@W1);  H(hi/lo) = prelu(dn*(T'n + sum T's) + b1)
    gemm_lds<<<gblocks, 512, 0, stream>>>(Xh, Xl, W1h, W1l, dis, Tp, N);
    aggregate8<<<ablocks, 256, 0, stream>>>(Tp, row_ptr, csr_src, dis, b1, alpha,
                                            nullptr, Xh /*Hh*/, Xl /*Hl*/, N, 1);
    // layer 2: T' = dis * (H@W2);  out = dn*(T'n + sum T's) + b2
    gemm_lds<<<gblocks, 512, 0, stream>>>(Xh /*Hh*/, Xl /*Hl*/, W2h, W2l, dis, Tp, N);
    aggregate8<<<ablocks, 256, 0, stream>>>(Tp, row_ptr, csr_src, dis, b2, alpha,
                                            outf, nullptr, nullptr, N, 0);
}

// Round 11
// 688.057 us; speedup vs baseline: 1.8109x; 1.0514x over previous
//
#include <hip/hip_runtime.h>
#include <cstdint>
#include <cstddef>

// -------- GCN 2-layer: out = A_norm @ prelu(A_norm @ (x W1) + b1) @ W2 + b2 --------
// A_norm = D^-1/2 (A + I) D^-1/2, deg = in-degree + 1 (PyG GCNConv default).
// edge_index arrives int32 [2][E]: src = ei[e], dst = ei[E + e].
//
// Round 11 vs round 10 (aggregates + gemm_lds proven, untouched):
//  * bucket_scan: serial 1-thread loop (196 dependent global RTs ~30us) -> one
//    256-thread LDS scan (~2us).
//  * split_x killed: gemm1 (gemm_f32a) reads x fp32 and converts to hi/lo bf16
//    in-register (identical math, no 204MB extra pass).
//  * dis folded into passB (counts already in LDS); prep_w single launch for W1+W2.
// Aggregate: one wave/node, 64-edge batched index loads + readlane, x8 ILP.
// GEMM: B hi/lo staged in LDS (132KB, pad 8), per-wave 64x128, 3-term hi/lo split.

#define IN_C 256
#define BSHIFT 9
#define BCAP 24576   // bucket capacity (avg ~16.3K edges/bucket; huge margin)

typedef __attribute__((ext_vector_type(8))) short bf16x8;
typedef __attribute__((ext_vector_type(4))) float f32x4;

__device__ __forceinline__ ushort f2bf(float x) {
    union { float f; uint32_t u; } v; v.f = x;
    uint32_t r = v.u + 0x7FFF + ((v.u >> 16) & 1);   // round-to-nearest-even
    return (ushort)(r >> 16);
}
__device__ __forceinline__ float bf2f(ushort b) {
    union { uint32_t u; float f; } v; v.u = ((uint32_t)b) << 16;
    return v.f;
}

// ---------------- CSR build: passA (bucket scatter, 4096 edges/block) ----------------
__global__ __launch_bounds__(256) void passA(const int* __restrict__ ei,
                                             int* __restrict__ bucketCnt,
                                             int2* __restrict__ bucketBuf, int E, int NB) {
    __shared__ int hist[256];
    __shared__ int gbase[256];
    __shared__ int cur[256];
    int tid = threadIdx.x;
    hist[tid] = 0; cur[tid] = 0;
    __syncthreads();
    int e0 = blockIdx.x * 4096;
    int src_r[16], dst_r[16];
#pragma unroll
    for (int i = 0; i < 16; ++i) {
        int e = e0 + i * 256 + tid;
        if (e < E) {
            src_r[i] = ei[e];
            dst_r[i] = ei[(size_t)E + e];
            atomicAdd(&hist[dst_r[i] >> BSHIFT], 1);
        } else dst_r[i] = -1;
    }
    __syncthreads();
    if (tid < NB && hist[tid] > 0) gbase[tid] = atomicAdd(&bucketCnt[tid], hist[tid]);
    __syncthreads();
#pragma unroll
    for (int i = 0; i < 16; ++i) {
        if (dst_r[i] >= 0) {
            int b = dst_r[i] >> BSHIFT;
            int p = atomicAdd(&cur[b], 1);
            int pos = gbase[b] + p;
            if (pos < BCAP) bucketBuf[(size_t)b * BCAP + pos] = make_int2(src_r[i], dst_r[i]);
        }
    }
}

// ---------------- CSR build: bucket base scan (one 256-thread LDS scan) ----------------
__global__ __launch_bounds__(256) void bucket_scanP(const int* __restrict__ bucketCnt,
                                                    int* __restrict__ bucket_base,
                                                    int* __restrict__ row_ptr, int NB, int N) {
    __shared__ int sdata[256];
    int tid = threadIdx.x;
    int c = 0;
    if (tid < NB) { c = bucketCnt[tid]; if (c > BCAP) c = BCAP; }
    sdata[tid] = c;
    __syncthreads();
    for (int o = 1; o < 256; o <<= 1) {
        int add = (tid >= o) ? sdata[tid - o] : 0;
        __syncthreads();
        sdata[tid] += add;
        __syncthreads();
    }
    if (tid < NB) bucket_base[tid] = sdata[tid] - c;
    if (tid == 255) row_ptr[N] = sdata[255];
}

// ------- CSR build: passB (one block per bucket; local CSR in LDS; writes dis) -------
__global__ __launch_bounds__(256) void passB(const int2* __restrict__ bucketBuf,
                                             const int* __restrict__ bucketCnt,
                                             const int* __restrict__ bucket_base,
                                             int* __restrict__ row_ptr,
                                             int* __restrict__ csr_src,
                                             float* __restrict__ dis, int N) {
    __shared__ int cnt[512];
    __shared__ int ofs[512];
    __shared__ int ssum[256];
    int b = blockIdx.x, tid = threadIdx.x;
    int base_node = b << BSHIFT;
    int nnodes = N - base_node; if (nnodes > 512) nnodes = 512;
    int nE = bucketCnt[b]; if (nE > BCAP) nE = BCAP;
    const int2* buf = bucketBuf + (size_t)b * BCAP;
    cnt[tid] = 0; cnt[tid + 256] = 0;
    __syncthreads();
    for (int i = tid; i < nE; i += 256) {
        int2 p = buf[i];
        atomicAdd(&cnt[p.y - base_node], 1);
    }
    __syncthreads();
    int c0 = cnt[2 * tid], c1 = cnt[2 * tid + 1];
    int s = c0 + c1;
    ssum[tid] = s;
    __syncthreads();
    for (int o = 1; o < 256; o <<= 1) {
        int add = (tid >= o) ? ssum[tid - o] : 0;
        __syncthreads();
        ssum[tid] += add;
        __syncthreads();
    }
    int run = ssum[tid] - s;           // exclusive within bucket
    int gb = bucket_base[b];
    int o0 = gb + run, o1 = gb + run + c0;
    ofs[2 * tid] = o0; ofs[2 * tid + 1] = o1;
    if (2 * tid < nnodes) {
        row_ptr[base_node + 2 * tid] = o0;
        dis[base_node + 2 * tid] = rsqrtf((float)(c0 + 1));
    }
    if (2 * tid + 1 < nnodes) {
        row_ptr[base_node + 2 * tid + 1] = o1;
        dis[base_node + 2 * tid + 1] = rsqrtf((float)(c1 + 1));
    }
    __syncthreads();
    for (int i = tid; i < nE; i += 256) {
        int2 p = buf[i];
        int pos = atomicAdd(&ofs[p.y - base_node], 1);
        csr_src[pos] = p.x;            // ~96KB window: L2-aggregated writeback
    }
}

// ------- weight prep (both layers, one launch): W[k][n] f32 -> WT[n][k] hi/lo bf16 -------
__global__ __launch_bounds__(256) void prep_w2(const float* __restrict__ W1,
                                               const float* __restrict__ W2,
                                               ushort* __restrict__ W1h, ushort* __restrict__ W1l,
                                               ushort* __restrict__ W2h, ushort* __restrict__ W2l) {
    int id = blockIdx.x * 256 + threadIdx.x;   // 131072
    const float* W = (id < 65536) ? W1 : W2;
    ushort* Th = (id < 65536) ? W1h : W2h;
    ushort* Tl = (id < 65536) ? W1l : W2l;
    int lid = id & 65535;
    int n = lid >> 8, k = lid & 255;
    float w = W[k * 256 + n];
    ushort h = f2bf(w);
    Th[lid] = h;
    Tl[lid] = f2bf(w - bf2f(h));
}

// ------- LDS-B MFMA GEMM (A = fp32, in-register hi/lo split): layer 1 -------
// T'(bf16)[M][256] = dis[r] * (A @ W). Block: 512 thr (8 waves), 512 rows x 128 cols.
__global__ __launch_bounds__(512, 2) void gemm_f32a(const float* __restrict__ A,
                                                    const ushort* __restrict__ Bh,
                                                    const ushort* __restrict__ Bl,
                                                    const float* __restrict__ dis,
                                                    ushort* __restrict__ C, int M) {
    __shared__ ushort Bsh[128][264];
    __shared__ ushort Bsl[128][264];
    int tid = threadIdx.x;
    int col0 = (blockIdx.x & 1) << 7;
    int brow = (blockIdx.x >> 1) << 9;
#pragma unroll
    for (int i = 0; i < 8; ++i) {
        int u = tid + i * 512;
        int cb = u >> 5, ko = (u & 31) * 8;
        *(bf16x8*)&Bsh[cb][ko] = *(const bf16x8*)&Bh[(size_t)(col0 + cb) * 256 + ko];
        *(bf16x8*)&Bsl[cb][ko] = *(const bf16x8*)&Bl[(size_t)(col0 + cb) * 256 + ko];
    }
    __syncthreads();

    int wave = tid >> 6, lane = tid & 63;
    int row0 = brow + wave * 64;
    if (row0 >= M) return;
    int lrow = lane & 15, lk = (lane >> 4) * 8;

    f32x4 acc[4][8];
#pragma unroll
    for (int i = 0; i < 4; ++i)
#pragma unroll
        for (int j = 0; j < 8; ++j) acc[i][j] = (f32x4)0.f;

#pragma unroll
    for (int ks = 0; ks < 8; ++ks) {
        int kb = ks * 32 + lk;
        bf16x8 ah[4], al[4];
#pragma unroll
        for (int i = 0; i < 4; ++i) {
            int row = row0 + i * 16 + lrow;
            if (row < M) {
                float4 f0 = *(const float4*)&A[(size_t)row * 256 + kb];
                float4 f1 = *(const float4*)&A[(size_t)row * 256 + kb + 4];
                float f[8] = {f0.x, f0.y, f0.z, f0.w, f1.x, f1.y, f1.z, f1.w};
#pragma unroll
                for (int k = 0; k < 8; ++k) {
                    ushort h = f2bf(f[k]);
                    ah[i][k] = (short)h;
                    al[i][k] = (short)f2bf(f[k] - bf2f(h));
                }
            } else {
                ah[i] = (bf16x8)(short)0;
                al[i] = (bf16x8)(short)0;
            }
        }
#pragma unroll
        for (int j = 0; j < 8; ++j) {
            bf16x8 bh = *(bf16x8*)&Bsh[j * 16 + lrow][kb];
            bf16x8 bl = *(bf16x8*)&Bsl[j * 16 + lrow][kb];
#pragma unroll
            for (int i = 0; i < 4; ++i) {
                acc[i][j] = __builtin_amdgcn_mfma_f32_16x16x32_bf16(ah[i], bh, acc[i][j], 0, 0, 0);
                acc[i][j] = __builtin_amdgcn_mfma_f32_16x16x32_bf16(ah[i], bl, acc[i][j], 0, 0, 0);
                acc[i][j] = __builtin_amdgcn_mfma_f32_16x16x32_bf16(al[i], bh, acc[i][j], 0, 0, 0);
            }
        }
    }
    int rb = (lane >> 4) * 4;
#pragma unroll
    for (int i = 0; i < 4; ++i) {
#pragma unroll
        for (int r = 0; r < 4; ++r) {
            int row = row0 + i * 16 + rb + r;
            if (row >= M) continue;
            float dr = dis[row];
#pragma unroll
            for (int j = 0; j < 8; ++j) {
                int col = col0 + j * 16 + lrow;
                C[(size_t)row * 256 + col] = f2bf(dr * acc[i][j][r]);
            }
        }
    }
}

// ------- LDS-B MFMA GEMM (A = hi/lo bf16 planes): layer 2 -------
__global__ __launch_bounds__(512, 2) void gemm_lds(const ushort* __restrict__ Ah,
                                                   const ushort* __restrict__ Al,
                                                   const ushort* __restrict__ Bh,
                                                   const ushort* __restrict__ Bl,
                                                   const float* __restrict__ dis,
                                                   ushort* __restrict__ C, int M) {
    __shared__ ushort Bsh[128][264];
    __shared__ ushort Bsl[128][264];
    int tid = threadIdx.x;
    int col0 = (blockIdx.x & 1) << 7;
    int brow = (blockIdx.x >> 1) << 9;
#pragma unroll
    for (int i = 0; i < 8; ++i) {
        int u = tid + i * 512;
        int cb = u >> 5, ko = (u & 31) * 8;
        *(bf16x8*)&Bsh[cb][ko] = *(const bf16x8*)&Bh[(size_t)(col0 + cb) * 256 + ko];
        *(bf16x8*)&Bsl[cb][ko] = *(const bf16x8*)&Bl[(size_t)(col0 + cb) * 256 + ko];
    }
    __syncthreads();

    int wave = tid >> 6, lane = tid & 63;
    int row0 = brow + wave * 64;
    if (row0 >= M) return;
    int lrow = lane & 15, lk = (lane >> 4) * 8;

    f32x4 acc[4][8];
#pragma unroll
    for (int i = 0; i < 4; ++i)
#pragma unroll
        for (int j = 0; j < 8; ++j) acc[i][j] = (f32x4)0.f;

#pragma unroll
    for (int ks = 0; ks < 8; ++ks) {
        int kb = ks * 32 + lk;
        bf16x8 ah[4], al[4];
#pragma unroll
        for (int i = 0; i < 4; ++i) {
            int row = row0 + i * 16 + lrow;
            if (row < M) {
                ah[i] = *(const bf16x8*)&Ah[(size_t)row * 256 + kb];
                al[i] = *(const bf16x8*)&Al[(size_t)row * 256 + kb];
            } else {
                ah[i] = (bf16x8)(short)0;
                al[i] = (bf16x8)(short)0;
            }
        }
#pragma unroll
        for (int j = 0; j < 8; ++j) {
            bf16x8 bh = *(bf16x8*)&Bsh[j * 16 + lrow][kb];
            bf16x8 bl = *(bf16x8*)&Bsl[j * 16 + lrow][kb];
#pragma unroll
            for (int i = 0; i < 4; ++i) {
                acc[i][j] = __builtin_amdgcn_mfma_f32_16x16x32_bf16(ah[i], bh, acc[i][j], 0, 0, 0);
                acc[i][j] = __builtin_amdgcn_mfma_f32_16x16x32_bf16(ah[i], bl, acc[i][j], 0, 0, 0);
                acc[i][j] = __builtin_amdgcn_mfma_f32_16x16x32_bf16(al[i], bh, acc[i][j], 0, 0, 0);
            }
        }
    }
    int rb = (lane >> 4) * 4;
#pragma unroll
    for (int i = 0; i < 4; ++i) {
#pragma unroll
        for (int r = 0; r < 4; ++r) {
            int row = row0 + i * 16 + rb + r;
            if (row >= M) continue;
            float dr = dis[row];
#pragma unroll
            for (int j = 0; j < 8; ++j) {
                int col = col0 + j * 16 + lrow;
                C[(size_t)row * 256 + col] = f2bf(dr * acc[i][j][r]);
            }
        }
    }
}

// ---------------- aggregate: out[n] = dis[n]*(T'[n] + sum_e T'[src_e]) + b ----------------
__global__ __launch_bounds__(256) void aggregate8(const ushort* __restrict__ Tp,
                                                  const int* __restrict__ row_ptr,
                                                  const int* __restrict__ csr_src,
                                                  const float* __restrict__ dis,
                                                  const float* __restrict__ bias,
                                                  const float* __restrict__ alpha_p,
                                                  float* __restrict__ outf,
                                                  ushort* __restrict__ outh,
                                                  ushort* __restrict__ outl,
                                                  int N, int mode) {
    int wave = threadIdx.x >> 6;
    int lane = threadIdx.x & 63;
    int n = blockIdx.x * 4 + wave;
    if (n >= N) return;
    int c = lane * 4;

    float ax[8], ay[8], az[8], aw[8];
#pragma unroll
    for (int t = 0; t < 8; ++t) { ax[t] = 0.f; ay[t] = 0.f; az[t] = 0.f; aw[t] = 0.f; }
    {
        ushort4 sv = *(const ushort4*)&Tp[(size_t)n * 256 + c];
        ax[0] = bf2f(sv.x); ay[0] = bf2f(sv.y); az[0] = bf2f(sv.z); aw[0] = bf2f(sv.w);
    }

    int e0 = row_ptr[n], e1 = row_ptr[n + 1];
    for (int base = e0; base < e1; base += 64) {
        int rem = e1 - base;
        int m = rem < 64 ? rem : 64;
        int idx = csr_src[base + (lane < m ? lane : 0)];
        int j = 0;
        for (; j + 8 <= m; j += 8) {
            int s[8];
            ushort4 v[8];
#pragma unroll
            for (int t = 0; t < 8; ++t) s[t] = __builtin_amdgcn_readlane(idx, j + t);
#pragma unroll
            for (int t = 0; t < 8; ++t) v[t] = *(const ushort4*)&Tp[(size_t)s[t] * 256 + c];
#pragma unroll
            for (int t = 0; t < 8; ++t) {
                ax[t] += bf2f(v[t].x); ay[t] += bf2f(v[t].y);
                az[t] += bf2f(v[t].z); aw[t] += bf2f(v[t].w);
            }
        }
        for (; j < m; ++j) {
            int s = __builtin_amdgcn_readlane(idx, j);
            ushort4 v = *(const ushort4*)&Tp[(size_t)s * 256 + c];
            ax[0] += bf2f(v.x); ay[0] += bf2f(v.y); az[0] += bf2f(v.z); aw[0] += bf2f(v.w);
        }
    }
#pragma unroll
    for (int t = 1; t < 8; ++t) { ax[0] += ax[t]; ay[0] += ay[t]; az[0] += az[t]; aw[0] += aw[t]; }

    float dn = dis[n];
    float4 bv = *(const float4*)&bias[c];
    float rx = dn * ax[0] + bv.x;
    float ry = dn * ay[0] + bv.y;
    float rz = dn * az[0] + bv.z;
    float rw = dn * aw[0] + bv.w;
    if (mode) {
        float al = *alpha_p;
        rx = rx >= 0.f ? rx : al * rx;
        ry = ry >= 0.f ? ry : al * ry;
        rz = rz >= 0.f ? rz : al * rz;
        rw = rw >= 0.f ? rw : al * rw;
        ushort hx = f2bf(rx), hy = f2bf(ry), hz = f2bf(rz), hw = f2bf(rw);
        *(ushort4*)&outh[(size_t)n * 256 + c] = make_ushort4(hx, hy, hz, hw);
        *(ushort4*)&outl[(size_t)n * 256 + c] = make_ushort4(f2bf(rx - bf2f(hx)), f2bf(ry - bf2f(hy)),
                                                             f2bf(rz - bf2f(hz)), f2bf(rw - bf2f(hw)));
    } else {
        f32x4 r; r.x = rx; r.y = ry; r.z = rz; r.w = rw;
        __builtin_nontemporal_store(r, (f32x4*)&outf[(size_t)n * 256 + c]);
    }
}

extern "C" void kernel_launch(void* const* d_in, const int* in_sizes, int n_in,
                              void* d_out, int out_size, void* d_ws, size_t ws_size,
                              hipStream_t stream) {
    const float* x = (const float*)d_in[0];
    const int* ei = (const int*)d_in[1];          // int32 (harness converts int64 -> int32)
    const float* W1 = (const float*)d_in[2];
    const float* b1 = (const float*)d_in[3];
    const float* W2 = (const float*)d_in[4];
    const float* b2 = (const float*)d_in[5];
    const float* alpha = (const float*)d_in[6];
    int N = in_sizes[0] / IN_C;
    int E = in_sizes[1] / 2;
    int NB = (N + 511) >> BSHIFT;
    if (NB > 256) return;                          // clean fail on unexpected N

    // ---- workspace layout (~116 MB, within proven footprint) ----
    char* ws = (char*)d_ws;
    size_t off = 0;
    auto alloc = [&](size_t bytes) {
        void* p = ws + off;
        off = (off + bytes + 255) & ~(size_t)255;
        return p;
    };
    int* row_ptr     = (int*)alloc(((size_t)N + 1) * 4);
    float* dis       = (float*)alloc((size_t)N * 4);
    int* csr_src     = (int*)alloc((size_t)E * 4);
    int* bucketCnt   = (int*)alloc(256 * 4);
    int* bucket_base = (int*)alloc(256 * 4);
    ushort* Tp       = (ushort*)alloc((size_t)N * IN_C * 2);   // 51.2 MB (bucketBuf alias)
    ushort* Hl       = (ushort*)alloc((size_t)N * IN_C * 2);   // 51.2 MB
    if (off > ws_size) return;                     // clean fail if ws too small
    int2* bucketBuf = (int2*)Tp;                   // dead before gemm1 writes Tp
    if ((size_t)NB * BCAP * 8 > (size_t)N * IN_C * 2) return;  // alias capacity guard

    // ---- d_out doubles as scratch (dead before final write) ----
    char* dob = (char*)d_out;
    ushort* Hh  = (ushort*)dob;
    ushort* W1h = (ushort*)(dob + (size_t)N * IN_C * 2);
    ushort* W1l = W1h + 65536;
    ushort* W2h = W1h + 131072;
    ushort* W2l = W1h + 196608;
    float* outf = (float*)d_out;

    hipMemsetAsync(bucketCnt, 0, 256 * 4, stream);

    // ---- CSR build (bucketed; passB also writes dis) ----
    passA<<<(E + 4095) / 4096, 256, 0, stream>>>(ei, bucketCnt, bucketBuf, E, NB);
    bucket_scanP<<<1, 256, 0, stream>>>(bucketCnt, bucket_base, row_ptr, NB, N);
    passB<<<NB, 256, 0, stream>>>(bucketBuf, bucketCnt, bucket_base, row_ptr, csr_src, dis, N);

    // ---- weight prep (single launch for both layers) ----
    prep_w2<<<512, 256, 0, stream>>>(W1, W2, W1h, W1l, W2h, W2l);

    int gblocks = ((N + 511) / 512) * 2;
    int ablocks = (N + 3) / 4;

    // layer 1: T' = dis * (x@W1)  (x fp32, in-register split);  H = prelu(...)
    gemm_f32a<<<gblocks, 512, 0, stream>>>(x, W1h, W1l, dis, Tp, N);
    aggregate8<<<ablocks, 256, 0, stream>>>(Tp, row_ptr, csr_src, dis, b1, alpha,
                                            nullptr, Hh, Hl, N, 1);
    // layer 2: T' = dis * (H@W2);  out = dn*(T'n + sum T's) + b2
    gemm_lds<<<gblocks, 512, 0, stream>>>(Hh, Hl, W2h, W2l, dis, Tp, N);
    aggregate8<<<ablocks, 256, 0, stream>>>(Tp, row_ptr, csr_src, dis, b2, alpha,
                                            outf, nullptr, nullptr, N, 0);
}

// Round 12
// 649.468 us; speedup vs baseline: 1.9185x; 1.0594x over previous
//
#include <hip/hip_runtime.h>
#include <cstdint>
#include <cstddef>

// -------- GCN 2-layer: out = A_norm @ prelu(A_norm @ (x W1) + b1) @ W2 + b2 --------
// A_norm = D^-1/2 (A + I) D^-1/2, deg = in-degree + 1 (PyG GCNConv default).
// edge_index arrives int32 [2][E]: src = ei[e], dst = ei[E + e].
//
// Round 12 vs round 11:
//  * passA payload packed to ONE uint per edge (src:17b | dst-local:9b) -> bucket
//    buffer traffic halved (write 12.8 MB, read 12.8 MB).
//  * H stored as pure bf16 (hi plane only; lo dropped). Error headroom: absmax was
//    1.95e-3 = 1 bf16 ULP vs 5.6e-3 threshold; predicted ~3.5e-3 after. gemm2 is
//    2-term (Ah*Bh + Ah*Bl); aggregate1 writes half the bytes.
// Aggregate: one wave/node, 64-edge batched index loads + readlane, x8 ILP
// (proven fabric-bound at 7.5 TB/s delivered; unchanged).
// GEMM: B hi/lo staged in LDS (132KB, pad 8), per-wave 64x128.

#define IN_C 256
#define BSHIFT 9
#define BCAP 24576   // bucket capacity (avg ~16.3K edges/bucket; huge margin)

typedef __attribute__((ext_vector_type(8))) short bf16x8;
typedef __attribute__((ext_vector_type(4))) float f32x4;

__device__ __forceinline__ ushort f2bf(float x) {
    union { float f; uint32_t u; } v; v.f = x;
    uint32_t r = v.u + 0x7FFF + ((v.u >> 16) & 1);   // round-to-nearest-even
    return (ushort)(r >> 16);
}
__device__ __forceinline__ float bf2f(ushort b) {
    union { uint32_t u; float f; } v; v.u = ((uint32_t)b) << 16;
    return v.f;
}

// ---------------- CSR build: passA (bucket scatter, packed payload) ----------------
__global__ __launch_bounds__(256) void passA(const int* __restrict__ ei,
                                             int* __restrict__ bucketCnt,
                                             uint32_t* __restrict__ bucketBuf, int E, int NB) {
    __shared__ int hist[256];
    __shared__ int gbase[256];
    __shared__ int cur[256];
    int tid = threadIdx.x;
    hist[tid] = 0; cur[tid] = 0;
    __syncthreads();
    int e0 = blockIdx.x * 4096;
    int src_r[16], dst_r[16];
#pragma unroll
    for (int i = 0; i < 16; ++i) {
        int e = e0 + i * 256 + tid;
        if (e < E) {
            src_r[i] = ei[e];
            dst_r[i] = ei[(size_t)E + e];
            atomicAdd(&hist[dst_r[i] >> BSHIFT], 1);
        } else dst_r[i] = -1;
    }
    __syncthreads();
    if (tid < NB && hist[tid] > 0) gbase[tid] = atomicAdd(&bucketCnt[tid], hist[tid]);
    __syncthreads();
#pragma unroll
    for (int i = 0; i < 16; ++i) {
        if (dst_r[i] >= 0) {
            int b = dst_r[i] >> BSHIFT;
            int p = atomicAdd(&cur[b], 1);
            int pos = gbase[b] + p;
            if (pos < BCAP)
                bucketBuf[(size_t)b * BCAP + pos] =
                    (uint32_t)src_r[i] | ((uint32_t)(dst_r[i] & 511) << 17);
        }
    }
}

// ---------------- CSR build: bucket base scan (one 256-thread LDS scan) ----------------
__global__ __launch_bounds__(256) void bucket_scanP(const int* __restrict__ bucketCnt,
                                                    int* __restrict__ bucket_base,
                                                    int* __restrict__ row_ptr, int NB, int N) {
    __shared__ int sdata[256];
    int tid = threadIdx.x;
    int c = 0;
    if (tid < NB) { c = bucketCnt[tid]; if (c > BCAP) c = BCAP; }
    sdata[tid] = c;
    __syncthreads();
    for (int o = 1; o < 256; o <<= 1) {
        int add = (tid >= o) ? sdata[tid - o] : 0;
        __syncthreads();
        sdata[tid] += add;
        __syncthreads();
    }
    if (tid < NB) bucket_base[tid] = sdata[tid] - c;
    if (tid == 255) row_ptr[N] = sdata[255];
}

// ------- CSR build: passB (one block per bucket; local CSR in LDS; writes dis) -------
__global__ __launch_bounds__(256) void passB(const uint32_t* __restrict__ bucketBuf,
                                             const int* __restrict__ bucketCnt,
                                             const int* __restrict__ bucket_base,
                                             int* __restrict__ row_ptr,
                                             int* __restrict__ csr_src,
                                             float* __restrict__ dis, int N) {
    __shared__ int cnt[512];
    __shared__ int ofs[512];
    __shared__ int ssum[256];
    int b = blockIdx.x, tid = threadIdx.x;
    int base_node = b << BSHIFT;
    int nnodes = N - base_node; if (nnodes > 512) nnodes = 512;
    int nE = bucketCnt[b]; if (nE > BCAP) nE = BCAP;
    const uint32_t* buf = bucketBuf + (size_t)b * BCAP;
    cnt[tid] = 0; cnt[tid + 256] = 0;
    __syncthreads();
    for (int i = tid; i < nE; i += 256) {
        atomicAdd(&cnt[buf[i] >> 17], 1);
    }
    __syncthreads();
    int c0 = cnt[2 * tid], c1 = cnt[2 * tid + 1];
    int s = c0 + c1;
    ssum[tid] = s;
    __syncthreads();
    for (int o = 1; o < 256; o <<= 1) {
        int add = (tid >= o) ? ssum[tid - o] : 0;
        __syncthreads();
        ssum[tid] += add;
        __syncthreads();
    }
    int run = ssum[tid] - s;           // exclusive within bucket
    int gb = bucket_base[b];
    int o0 = gb + run, o1 = gb + run + c0;
    ofs[2 * tid] = o0; ofs[2 * tid + 1] = o1;
    if (2 * tid < nnodes) {
        row_ptr[base_node + 2 * tid] = o0;
        dis[base_node + 2 * tid] = rsqrtf((float)(c0 + 1));
    }
    if (2 * tid + 1 < nnodes) {
        row_ptr[base_node + 2 * tid + 1] = o1;
        dis[base_node + 2 * tid + 1] = rsqrtf((float)(c1 + 1));
    }
    __syncthreads();
    for (int i = tid; i < nE; i += 256) {
        uint32_t p = buf[i];
        int pos = atomicAdd(&ofs[p >> 17], 1);
        csr_src[pos] = (int)(p & 0x1FFFF);
    }
}

// ------- weight prep (both layers, one launch): W[k][n] f32 -> WT[n][k] hi/lo bf16 -------
__global__ __launch_bounds__(256) void prep_w2(const float* __restrict__ W1,
                                               const float* __restrict__ W2,
                                               ushort* __restrict__ W1h, ushort* __restrict__ W1l,
                                               ushort* __restrict__ W2h, ushort* __restrict__ W2l) {
    int id = blockIdx.x * 256 + threadIdx.x;   // 131072
    const float* W = (id < 65536) ? W1 : W2;
    ushort* Th = (id < 65536) ? W1h : W2h;
    ushort* Tl = (id < 65536) ? W1l : W2l;
    int lid = id & 65535;
    int n = lid >> 8, k = lid & 255;
    float w = W[k * 256 + n];
    ushort h = f2bf(w);
    Th[lid] = h;
    Tl[lid] = f2bf(w - bf2f(h));
}

// ------- LDS-B MFMA GEMM (A = fp32, in-register hi/lo split, 3-term): layer 1 -------
__global__ __launch_bounds__(512, 2) void gemm_f32a(const float* __restrict__ A,
                                                    const ushort* __restrict__ Bh,
                                                    const ushort* __restrict__ Bl,
                                                    const float* __restrict__ dis,
                                                    ushort* __restrict__ C, int M) {
    __shared__ ushort Bsh[128][264];
    __shared__ ushort Bsl[128][264];
    int tid = threadIdx.x;
    int col0 = (blockIdx.x & 1) << 7;
    int brow = (blockIdx.x >> 1) << 9;
#pragma unroll
    for (int i = 0; i < 8; ++i) {
        int u = tid + i * 512;
        int cb = u >> 5, ko = (u & 31) * 8;
        *(bf16x8*)&Bsh[cb][ko] = *(const bf16x8*)&Bh[(size_t)(col0 + cb) * 256 + ko];
        *(bf16x8*)&Bsl[cb][ko] = *(const bf16x8*)&Bl[(size_t)(col0 + cb) * 256 + ko];
    }
    __syncthreads();

    int wave = tid >> 6, lane = tid & 63;
    int row0 = brow + wave * 64;
    if (row0 >= M) return;
    int lrow = lane & 15, lk = (lane >> 4) * 8;

    f32x4 acc[4][8];
#pragma unroll
    for (int i = 0; i < 4; ++i)
#pragma unroll
        for (int j = 0; j < 8; ++j) acc[i][j] = (f32x4)0.f;

#pragma unroll
    for (int ks = 0; ks < 8; ++ks) {
        int kb = ks * 32 + lk;
        bf16x8 ah[4], al[4];
#pragma unroll
        for (int i = 0; i < 4; ++i) {
            int row = row0 + i * 16 + lrow;
            if (row < M) {
                float4 f0 = *(const float4*)&A[(size_t)row * 256 + kb];
                float4 f1 = *(const float4*)&A[(size_t)row * 256 + kb + 4];
                float f[8] = {f0.x, f0.y, f0.z, f0.w, f1.x, f1.y, f1.z, f1.w};
#pragma unroll
                for (int k = 0; k < 8; ++k) {
                    ushort h = f2bf(f[k]);
                    ah[i][k] = (short)h;
                    al[i][k] = (short)f2bf(f[k] - bf2f(h));
                }
            } else {
                ah[i] = (bf16x8)(short)0;
                al[i] = (bf16x8)(short)0;
            }
        }
#pragma unroll
        for (int j = 0; j < 8; ++j) {
            bf16x8 bh = *(bf16x8*)&Bsh[j * 16 + lrow][kb];
            bf16x8 bl = *(bf16x8*)&Bsl[j * 16 + lrow][kb];
#pragma unroll
            for (int i = 0; i < 4; ++i) {
                acc[i][j] = __builtin_amdgcn_mfma_f32_16x16x32_bf16(ah[i], bh, acc[i][j], 0, 0, 0);
                acc[i][j] = __builtin_amdgcn_mfma_f32_16x16x32_bf16(ah[i], bl, acc[i][j], 0, 0, 0);
                acc[i][j] = __builtin_amdgcn_mfma_f32_16x16x32_bf16(al[i], bh, acc[i][j], 0, 0, 0);
            }
        }
    }
    int rb = (lane >> 4) * 4;
#pragma unroll
    for (int i = 0; i < 4; ++i) {
#pragma unroll
        for (int r = 0; r < 4; ++r) {
            int row = row0 + i * 16 + rb + r;
            if (row >= M) continue;
            float dr = dis[row];
#pragma unroll
            for (int j = 0; j < 8; ++j) {
                int col = col0 + j * 16 + lrow;
                C[(size_t)row * 256 + col] = f2bf(dr * acc[i][j][r]);
            }
        }
    }
}

// ------- LDS-B MFMA GEMM (A = bf16 single plane, 2-term Ah*(Bh+Bl)): layer 2 -------
__global__ __launch_bounds__(512, 2) void gemm_h(const ushort* __restrict__ Ah,
                                                 const ushort* __restrict__ Bh,
                                                 const ushort* __restrict__ Bl,
                                                 const float* __restrict__ dis,
                                                 ushort* __restrict__ C, int M) {
    __shared__ ushort Bsh[128][264];
    __shared__ ushort Bsl[128][264];
    int tid = threadIdx.x;
    int col0 = (blockIdx.x & 1) << 7;
    int brow = (blockIdx.x >> 1) << 9;
#pragma unroll
    for (int i = 0; i < 8; ++i) {
        int u = tid + i * 512;
        int cb = u >> 5, ko = (u & 31) * 8;
        *(bf16x8*)&Bsh[cb][ko] = *(const bf16x8*)&Bh[(size_t)(col0 + cb) * 256 + ko];
        *(bf16x8*)&Bsl[cb][ko] = *(const bf16x8*)&Bl[(size_t)(col0 + cb) * 256 + ko];
    }
    __syncthreads();

    int wave = tid >> 6, lane = tid & 63;
    int row0 = brow + wave * 64;
    if (row0 >= M) return;
    int lrow = lane & 15, lk = (lane >> 4) * 8;

    f32x4 acc[4][8];
#pragma unroll
    for (int i = 0; i < 4; ++i)
#pragma unroll
        for (int j = 0; j < 8; ++j) acc[i][j] = (f32x4)0.f;

#pragma unroll
    for (int ks = 0; ks < 8; ++ks) {
        int kb = ks * 32 + lk;
        bf16x8 ah[4];
#pragma unroll
        for (int i = 0; i < 4; ++i) {
            int row = row0 + i * 16 + lrow;
            ah[i] = (row < M) ? *(const bf16x8*)&Ah[(size_t)row * 256 + kb]
                              : (bf16x8)(short)0;
        }
#pragma unroll
        for (int j = 0; j < 8; ++j) {
            bf16x8 bh = *(bf16x8*)&Bsh[j * 16 + lrow][kb];
            bf16x8 bl = *(bf16x8*)&Bsl[j * 16 + lrow][kb];
#pragma unroll
            for (int i = 0; i < 4; ++i) {
                acc[i][j] = __builtin_amdgcn_mfma_f32_16x16x32_bf16(ah[i], bh, acc[i][j], 0, 0, 0);
                acc[i][j] = __builtin_amdgcn_mfma_f32_16x16x32_bf16(ah[i], bl, acc[i][j], 0, 0, 0);
            }
        }
    }
    int rb = (lane >> 4) * 4;
#pragma unroll
    for (int i = 0; i < 4; ++i) {
#pragma unroll
        for (int r = 0; r < 4; ++r) {
            int row = row0 + i * 16 + rb + r;
            if (row >= M) continue;
            float dr = dis[row];
#pragma unroll
            for (int j = 0; j < 8; ++j) {
                int col = col0 + j * 16 + lrow;
                C[(size_t)row * 256 + col] = f2bf(dr * acc[i][j][r]);
            }
        }
    }
}

// ---------------- aggregate: out[n] = dis[n]*(T'[n] + sum_e T'[src_e]) + b ----------------
// one wave per node; 64-edge batched index loads + readlane broadcast, x8 ILP.
// mode 1: PReLU + bf16 hi plane only. mode 0: fp32 nontemporal.
__global__ __launch_bounds__(256) void aggregate8(const ushort* __restrict__ Tp,
                                                  const int* __restrict__ row_ptr,
                                                  const int* __restrict__ csr_src,
                                                  const float* __restrict__ dis,
                                                  const float* __restrict__ bias,
                                                  const float* __restrict__ alpha_p,
                                                  float* __restrict__ outf,
                                                  ushort* __restrict__ outh,
                                                  int N, int mode) {
    int wave = threadIdx.x >> 6;
    int lane = threadIdx.x & 63;
    int n = blockIdx.x * 4 + wave;
    if (n >= N) return;
    int c = lane * 4;

    float ax[8], ay[8], az[8], aw[8];
#pragma unroll
    for (int t = 0; t < 8; ++t) { ax[t] = 0.f; ay[t] = 0.f; az[t] = 0.f; aw[t] = 0.f; }
    {
        ushort4 sv = *(const ushort4*)&Tp[(size_t)n * 256 + c];
        ax[0] = bf2f(sv.x); ay[0] = bf2f(sv.y); az[0] = bf2f(sv.z); aw[0] = bf2f(sv.w);
    }

    int e0 = row_ptr[n], e1 = row_ptr[n + 1];
    for (int base = e0; base < e1; base += 64) {
        int rem = e1 - base;
        int m = rem < 64 ? rem : 64;
        int idx = csr_src[base + (lane < m ? lane : 0)];
        int j = 0;
        for (; j + 8 <= m; j += 8) {
            int s[8];
            ushort4 v[8];
#pragma unroll
            for (int t = 0; t < 8; ++t) s[t] = __builtin_amdgcn_readlane(idx, j + t);
#pragma unroll
            for (int t = 0; t < 8; ++t) v[t] = *(const ushort4*)&Tp[(size_t)s[t] * 256 + c];
#pragma unroll
            for (int t = 0; t < 8; ++t) {
                ax[t] += bf2f(v[t].x); ay[t] += bf2f(v[t].y);
                az[t] += bf2f(v[t].z); aw[t] += bf2f(v[t].w);
            }
        }
        for (; j < m; ++j) {
            int s = __builtin_amdgcn_readlane(idx, j);
            ushort4 v = *(const ushort4*)&Tp[(size_t)s * 256 + c];
            ax[0] += bf2f(v.x); ay[0] += bf2f(v.y); az[0] += bf2f(v.z); aw[0] += bf2f(v.w);
        }
    }
#pragma unroll
    for (int t = 1; t < 8; ++t) { ax[0] += ax[t]; ay[0] += ay[t]; az[0] += az[t]; aw[0] += aw[t]; }

    float dn = dis[n];
    float4 bv = *(const float4*)&bias[c];
    float rx = dn * ax[0] + bv.x;
    float ry = dn * ay[0] + bv.y;
    float rz = dn * az[0] + bv.z;
    float rw = dn * aw[0] + bv.w;
    if (mode) {
        float al = *alpha_p;
        rx = rx >= 0.f ? rx : al * rx;
        ry = ry >= 0.f ? ry : al * ry;
        rz = rz >= 0.f ? rz : al * rz;
        rw = rw >= 0.f ? rw : al * rw;
        *(ushort4*)&outh[(size_t)n * 256 + c] =
            make_ushort4(f2bf(rx), f2bf(ry), f2bf(rz), f2bf(rw));
    } else {
        f32x4 r; r.x = rx; r.y = ry; r.z = rz; r.w = rw;
        __builtin_nontemporal_store(r, (f32x4*)&outf[(size_t)n * 256 + c]);
    }
}

extern "C" void kernel_launch(void* const* d_in, const int* in_sizes, int n_in,
                              void* d_out, int out_size, void* d_ws, size_t ws_size,
                              hipStream_t stream) {
    const float* x = (const float*)d_in[0];
    const int* ei = (const int*)d_in[1];          // int32 (harness converts int64 -> int32)
    const float* W1 = (const float*)d_in[2];
    const float* b1 = (const float*)d_in[3];
    const float* W2 = (const float*)d_in[4];
    const float* b2 = (const float*)d_in[5];
    const float* alpha = (const float*)d_in[6];
    int N = in_sizes[0] / IN_C;
    int E = in_sizes[1] / 2;
    int NB = (N + 511) >> BSHIFT;
    if (NB > 256 || N > 131072) return;            // packed src needs 17 bits

    // ---- workspace layout (~65 MB) ----
    char* ws = (char*)d_ws;
    size_t off = 0;
    auto alloc = [&](size_t bytes) {
        void* p = ws + off;
        off = (off + bytes + 255) & ~(size_t)255;
        return p;
    };
    int* row_ptr     = (int*)alloc(((size_t)N + 1) * 4);
    float* dis       = (float*)alloc((size_t)N * 4);
    int* csr_src     = (int*)alloc((size_t)E * 4);
    int* bucketCnt   = (int*)alloc(256 * 4);
    int* bucket_base = (int*)alloc(256 * 4);
    ushort* Tp       = (ushort*)alloc((size_t)N * IN_C * 2);   // 51.2 MB (bucketBuf alias)
    if (off > ws_size) return;                     // clean fail if ws too small
    uint32_t* bucketBuf = (uint32_t*)Tp;           // dead before gemm1 writes Tp
    if ((size_t)NB * BCAP * 4 > (size_t)N * IN_C * 2) return;  // alias capacity guard

    // ---- d_out doubles as scratch (dead before final write) ----
    char* dob = (char*)d_out;
    ushort* Hh  = (ushort*)dob;
    ushort* W1h = (ushort*)(dob + (size_t)N * IN_C * 2);
    ushort* W1l = W1h + 65536;
    ushort* W2h = W1h + 131072;
    ushort* W2l = W1h + 196608;
    float* outf = (float*)d_out;

    hipMemsetAsync(bucketCnt, 0, 256 * 4, stream);

    // ---- CSR build (bucketed; passB also writes dis) ----
    passA<<<(E + 4095) / 4096, 256, 0, stream>>>(ei, bucketCnt, bucketBuf, E, NB);
    bucket_scanP<<<1, 256, 0, stream>>>(bucketCnt, bucket_base, row_ptr, NB, N);
    passB<<<NB, 256, 0, stream>>>(bucketBuf, bucketCnt, bucket_base, row_ptr, csr_src, dis, N);

    // ---- weight prep (single launch for both layers) ----
    prep_w2<<<512, 256, 0, stream>>>(W1, W2, W1h, W1l, W2h, W2l);

    int gblocks = ((N + 511) / 512) * 2;
    int ablocks = (N + 3) / 4;

    // layer 1: T' = dis * (x@W1)  (x fp32, in-register split);  H(bf16) = prelu(...)
    gemm_f32a<<<gblocks, 512, 0, stream>>>(x, W1h, W1l, dis, Tp, N);
    aggregate8<<<ablocks, 256, 0, stream>>>(Tp, row_ptr, csr_src, dis, b1, alpha,
                                            nullptr, Hh, N, 1);
    // layer 2: T' = dis * (H@W2) (2-term);  out = dn*(T'n + sum T's) + b2
    gemm_h<<<gblocks, 512, 0, stream>>>(Hh, W2h, W2l, dis, Tp, N);
    aggregate8<<<ablocks, 256, 0, stream>>>(Tp, row_ptr, csr_src, dis, b2, alpha,
                                            outf, nullptr, N, 0);
}